// Round 7
// baseline (22238.440 us; speedup 1.0000x reference)
//
#include <hip/hip_runtime.h>
#include <cstdint>
#include <cmath>
#include <cstring>

// =====================================================================
// TensorRingModel: Q=20 qubits, L=4 layers, R=24 bond rank.
//   host:  replicate np.random.default_rng(0) -> initial cores
//   dev :  evolve kernel (single WG, 384 thr = 24 teams x 16 lanes):
//          4x { RY layer; 20x [merge+CZ -> Brent-Luk register-resident
//          one-sided Jacobi, NO per-round barrier: intra-wave moves rely
//          on in-order wave DS; cross-wave handoffs use LDS flag sync
//          (skew<=1, parity ping-pong) -> truncate 24 -> sigma^-1.5*A^H M]}
//   dev :  ring transfer chain + traces -> d_out[0]
// =====================================================================

#define RK 24
#define NQ 20
#define NLAY 4
#define NCOL 48
#define AS 49          // padded complex column stride in LDS
#define NSWEEP 8       // max sweeps
#define NTHR 384       // 24 teams x 16 lanes (6 waves, 4 teams/wave)
#define CORE_ELEMS (RK * 2 * RK)      // 1152 complex per core
#define M4 (RK * RK * RK * RK)        // 331776

// ---------------------------------------------------------------------
// Host-side exact replication of numpy default_rng(0).standard_normal
// ---------------------------------------------------------------------
namespace npyrng {

struct Pcg64 {
  unsigned __int128 state, inc;
  static inline unsigned __int128 mult() {
    return (((unsigned __int128)0x2360ED051FC65DA4ull) << 64) |
           0x4385DF649FCCF645ull;
  }
  inline void step() { state = state * mult() + inc; }
  inline uint64_t next64() {
    step();
    uint64_t hi = (uint64_t)(state >> 64), lo = (uint64_t)state;
    uint64_t v = hi ^ lo;
    unsigned r = (unsigned)(state >> 122);
    return (v >> r) | (v << ((64u - r) & 63u));
  }
  inline double nextDouble() {
    return (double)(next64() >> 11) * (1.0 / 9007199254740992.0);
  }
};

struct ZigTables {
  uint64_t ki[256];
  double wi[256], fi[256];
};

static void build_tables(ZigTables& T) {
  const double NR = 3.6541528853610088;
  const double PI = 3.14159265358979323846;
  double f = std::exp(-0.5 * NR * NR);
  double V = NR * f + std::sqrt(PI / 2.0) * std::erfc(NR / std::sqrt(2.0));
  const double m1 = 4503599627370496.0;  // 2^52
  double q = V / f;
  T.ki[0] = (uint64_t)((NR / q) * m1);
  T.ki[1] = 0;
  T.wi[0] = q / m1;
  T.wi[255] = NR / m1;
  T.fi[0] = 1.0;
  T.fi[255] = f;
  double tn = NR;
  for (int i = 254; i >= 1; --i) {
    double dn = std::sqrt(-2.0 * std::log(V / tn + std::exp(-0.5 * tn * tn)));
    T.ki[i + 1] = (uint64_t)((dn / tn) * m1);
    T.fi[i] = std::exp(-0.5 * dn * dn);
    T.wi[i] = dn / m1;
    tn = dn;
  }
}

static double std_normal(Pcg64& g, const ZigTables& T) {
  const double NR = 3.6541528853610088;
  const double INV_NR = 0.27366123732975828;
  for (;;) {
    uint64_t r = g.next64();
    int idx = (int)(r & 0xff);
    r >>= 8;
    int sign = (int)(r & 1);
    uint64_t rabs = (r >> 1) & 0x000fffffffffffffull;
    double x = (double)rabs * T.wi[idx];
    if (sign) x = -x;
    if (rabs < T.ki[idx]) return x;
    if (idx == 0) {
      for (;;) {
        double xx = -INV_NR * std::log1p(-g.nextDouble());
        double yy = -std::log1p(-g.nextDouble());
        if (yy + yy > xx * xx)
          return ((rabs >> 8) & 1) ? -(NR + xx) : (NR + xx);
      }
    } else {
      if ((T.fi[idx - 1] - T.fi[idx]) * g.nextDouble() + T.fi[idx] <
          std::exp(-0.5 * x * x))
        return x;
    }
  }
}

static void seed_pcg64_numpy0(Pcg64& g) {
  const uint32_t INIT_A = 0x43b0d7e5u, MULT_A = 0x931e8875u;
  const uint32_t INIT_B = 0x8b51f9ddu, MULT_B = 0x58f38dedu;
  const uint32_t MIX_L = 0xca01f9ddu, MIX_R = 0x4973f715u;
  uint32_t pool[4];
  uint32_t hc = INIT_A;
  auto hashf = [&](uint32_t value) -> uint32_t {
    value ^= hc;
    hc *= MULT_A;
    value *= hc;
    value ^= value >> 16;
    return value;
  };
  auto mixf = [&](uint32_t x, uint32_t y) -> uint32_t {
    uint32_t r = x * MIX_L - y * MIX_R;
    r ^= r >> 16;
    return r;
  };
  uint32_t entropy0 = 0u;
  for (int i = 0; i < 4; ++i) pool[i] = hashf(i < 1 ? entropy0 : 0u);
  for (int s = 0; s < 4; ++s)
    for (int d = 0; d < 4; ++d)
      if (s != d) pool[d] = mixf(pool[d], hashf(pool[s]));
  uint32_t w[8];
  uint32_t hb = INIT_B;
  for (int i = 0; i < 8; ++i) {
    uint32_t dv = pool[i & 3];
    dv ^= hb;
    hb *= MULT_B;
    dv *= hb;
    dv ^= dv >> 16;
    w[i] = dv;
  }
  uint64_t v0 = (uint64_t)w[0] | ((uint64_t)w[1] << 32);
  uint64_t v1 = (uint64_t)w[2] | ((uint64_t)w[3] << 32);
  uint64_t v2 = (uint64_t)w[4] | ((uint64_t)w[5] << 32);
  uint64_t v3 = (uint64_t)w[6] | ((uint64_t)w[7] << 32);
  unsigned __int128 initstate = (((unsigned __int128)v0) << 64) | v1;
  unsigned __int128 initseq = (((unsigned __int128)v2) << 64) | v3;
  g.state = 0;
  g.inc = (initseq << 1) | 1;
  g.step();
  g.state += initstate;
  g.step();
}

}  // namespace npyrng

static float h_cores[NQ * CORE_ELEMS * 2];

static void fill_host_cores() {
  npyrng::Pcg64 g;
  npyrng::seed_pcg64_numpy0(g);
  npyrng::ZigTables T;
  npyrng::build_tables(T);
  double re[CORE_ELEMS], im[CORE_ELEMS];
  for (int core = 0; core < NQ; ++core) {
    for (int t = 0; t < CORE_ELEMS; ++t) re[t] = npyrng::std_normal(g, T);
    for (int t = 0; t < CORE_ELEMS; ++t) im[t] = npyrng::std_normal(g, T);
    for (int o = 0; o < CORE_ELEMS; ++o) {
      int a = o / (2 * RK);
      int s = (o / RK) & 1;
      int b = o % RK;
      float baser = (s == 0 && a == b) ? 1.0f : 0.0f;
      float nr = (float)re[o], ni = (float)im[o];
      h_cores[(core * CORE_ELEMS + o) * 2 + 0] = baser + 0.01f * nr;
      h_cores[(core * CORE_ELEMS + o) * 2 + 1] = 0.01f * ni;
    }
  }
}

// ---------------------------------------------------------------------
// DPP rotate-reduce within each 16-lane row; all lanes end with the sum.
// ---------------------------------------------------------------------
__device__ __forceinline__ float row_reduce16(float x) {
  int v;
  v = __builtin_amdgcn_update_dpp(0, __float_as_int(x), 0x128, 0xf, 0xf, false);
  x += __int_as_float(v);
  v = __builtin_amdgcn_update_dpp(0, __float_as_int(x), 0x124, 0xf, 0xf, false);
  x += __int_as_float(v);
  v = __builtin_amdgcn_update_dpp(0, __float_as_int(x), 0x122, 0xf, 0xf, false);
  x += __int_as_float(v);
  v = __builtin_amdgcn_update_dpp(0, __float_as_int(x), 0x121, 0xf, 0xf, false);
  x += __int_as_float(v);
  return x;
}

// ---------------------------------------------------------------------
// Evolve kernel: 384 threads = 24 teams x 16 lanes = 6 waves x 4 teams.
// Brent-Luk systolic Jacobi, register-resident columns, barrier-free rounds:
//   - movement slots: team i always writes tdst/bdst, reads tsrc/bsrc.
//     Intra-wave producer/consumer pairs are the SAME wave -> in-order DS.
//   - cross-wave transfers (teams 3,7,11,15,19 top->right; 4,8,12,16,20
//     bot->left): LDS flag = last completed round rr. Receiver spins.
//     Bidirectional neighbor deps bound skew to <=1 round; A/S1 parity
//     ping-pong tolerates skew 1 (producer overwrites a parity slot at
//     rr+2 only after its spin proved the consumer finished rr+1, whose
//     body consumed the rr data).
//   - rr is GLOBAL (never reset) so flags stay monotone across SVDs.
// ---------------------------------------------------------------------
__global__ __launch_bounds__(NTHR) void evolve_kernel(
    const float* __restrict__ params, float2* __restrict__ cores) {
  __shared__ float2 A[NCOL * AS];     // staging buf 0 / merge + emit storage
  __shared__ float2 S1[NCOL * AS];    // staging buf 1
  __shared__ float2 M0[NCOL * NCOL];  // pristine merge matrix (also staging)
  __shared__ float n0[NCOL], n1[NCOL];  // norm staging (ping-pong)
  __shared__ float sig2[NCOL];        // exact norms^2 for emit
  __shared__ int keepSrc[RK];
  __shared__ float csbuf[NQ * 2];
  __shared__ int sweepFlag;
  __shared__ int flagR[6], flagL[6];  // last-completed-round per wave

  const int tid = threadIdx.x;
  const int team = tid >> 4;   // 0..23
  const int sub = tid & 15;    // 0..15
  const int wv = tid >> 6;     // 0..5

  // constant per-team movement destinations (circle method)
  const int tdst = (team == 0) ? 0 : ((team < 23) ? team + 1 : 47);
  const int bdst = (team == 0) ? 1 : (23 + team);
  const int tsrc = team;        // read-back slots
  const int bsrc = 24 + team;

  const bool sendR = ((team & 3) == 3) && (team < 23);  // 3,7,11,15,19
  const bool sendL = ((team & 3) == 0) && (team > 0);   // 4,8,12,16,20

  if (tid == 0) sweepFlag = 0;
  if (tid < 6) { flagR[tid] = -1; flagL[tid] = -1; }

  int rr = 0;  // GLOBAL round counter (parity + flag values), never reset

  for (int layer = 0; layer < NLAY; ++layer) {
    // ---- RY on every qubit ----
    if (tid < NQ) {
      float half = 0.5f * params[layer * NQ + tid];
      csbuf[2 * tid] = cosf(half);
      csbuf[2 * tid + 1] = sinf(half);
    }
    __syncthreads();
    for (int o = tid; o < NQ * RK * RK; o += NTHR) {
      int qq = o / (RK * RK);
      int ab = o % (RK * RK);
      int a = ab / RK, b = ab % RK;
      float ch = csbuf[2 * qq], sh = csbuf[2 * qq + 1];
      float2* base = cores + qq * CORE_ELEMS;
      float2 c0 = base[(a * 2 + 0) * RK + b];
      float2 c1 = base[(a * 2 + 1) * RK + b];
      base[(a * 2 + 0) * RK + b] =
          make_float2(ch * c0.x - sh * c1.x, ch * c0.y - sh * c1.y);
      base[(a * 2 + 1) * RK + b] =
          make_float2(sh * c0.x + ch * c1.x, sh * c0.y + ch * c1.y);
    }
    __syncthreads();

    // ---- ring of CZ with truncated SVD ----
    for (int qg = 0; qg < NQ; ++qg) {
      int jg = (qg + 1) % NQ;
      const float2* ci = cores + qg * CORE_ELEMS;
      const float2* cj = cores + jg * CORE_ELEMS;

      // stage ci, cj into M0 (exactly 2*1152 = 2304 slots)
      for (int o = tid; o < CORE_ELEMS; o += NTHR) {
        M0[o] = ci[o];
        M0[CORE_ELEMS + o] = cj[o];
      }
      __syncthreads();

      // M[(a*2+s)][(t*24+c)] = phase(s,t) * sum_b ci[a,s,b] cj[b,t,c]
      float2 mv[6];
      {
        int k = 0;
        for (int o = tid; o < NCOL * NCOL; o += NTHR, ++k) {
          int col = o / NCOL, row = o % NCOL;
          int a = row >> 1, s = row & 1;
          int t = col / RK, cc = col % RK;
          float accx = 0.f, accy = 0.f;
          for (int b = 0; b < RK; ++b) {
            float2 x = M0[(a * 2 + s) * RK + b];
            float2 y = M0[CORE_ELEMS + (b * 2 + t) * RK + cc];
            accx += x.x * y.x - x.y * y.y;
            accy += x.x * y.y + x.y * y.x;
          }
          if (s == 1 && t == 1) { accx = -accx; accy = -accy; }
          mv[k] = make_float2(accx, accy);
        }
      }
      __syncthreads();
      {
        int k = 0;
        for (int o = tid; o < NCOL * NCOL; o += NTHR, ++k) {
          int col = o / NCOL, row = o % NCOL;
          A[col * AS + row] = mv[k];
          M0[col * NCOL + row] = mv[k];
        }
      }
      __syncthreads();

      // ---- load this team's two columns into registers + norms ----
      float2 t0 = A[tsrc * AS + sub], t1 = A[tsrc * AS + sub + 16],
             t2 = A[tsrc * AS + sub + 32];
      float2 b0 = A[bsrc * AS + sub], b1 = A[bsrc * AS + sub + 16],
             b2 = A[bsrc * AS + sub + 32];
      float nt = t0.x * t0.x + t0.y * t0.y + t1.x * t1.x + t1.y * t1.y +
                 t2.x * t2.x + t2.y * t2.y;
      float nb = b0.x * b0.x + b0.y * b0.y + b1.x * b1.x + b1.y * b1.y +
                 b2.x * b2.x + b2.y * b2.y;
      nt = row_reduce16(nt);
      nb = row_reduce16(nb);
      // all teams must finish initial reads before any movement write may
      // clobber A slots (first-round parity can target A since rr is global)
      __syncthreads();

      // ---- Brent-Luk systolic Jacobi (barrier-free rounds) ----
      for (int sw = 0; sw < NSWEEP; ++sw) {
        bool myActive = false;
        for (int r = 0; r < 47; ++r) {
          // in-register complex dot: g = t^H b
          float pr = t0.x * b0.x + t0.y * b0.y + t1.x * b1.x + t1.y * b1.y +
                     t2.x * b2.x + t2.y * b2.y;
          float pi = t0.x * b0.y - t0.y * b0.x + t1.x * b1.y - t1.y * b1.x +
                     t2.x * b2.y - t2.y * b2.x;
          pr = row_reduce16(pr);
          pi = row_reduce16(pi);
          float m2 = pr * pr + pi * pi;
          myActive = myActive || (m2 > 1e-7f * nt * nb);
          if (m2 > 1e-30f && m2 > 1e-14f * nt * nb) {
            float inv_m = rsqrtf(m2);           // 1/|g|
            float zr = pr * inv_m, zi = pi * inv_m;
            float tau = (nt - nb) * 0.5f * inv_m;
            float tt = 1.f / (fabsf(tau) + sqrtf(1.f + tau * tau));
            if (tau < 0.f) tt = -tt;
            float cc_ = rsqrtf(1.f + tt * tt);
            float ss_ = tt * cc_;
#define ROT_PAIR(xp, xq)                                                     \
  {                                                                          \
    float zqr = zr * xq.x + zi * xq.y;                                       \
    float zqi = zr * xq.y - zi * xq.x;                                       \
    float zpr = zr * xp.x - zi * xp.y;                                       \
    float zpi = zr * xp.y + zi * xp.x;                                       \
    float2 npv = make_float2(cc_ * xp.x + ss_ * zqr, cc_ * xp.y + ss_ * zqi);\
    float2 nqv = make_float2(cc_ * xq.x - ss_ * zpr, cc_ * xq.y - ss_ * zpi);\
    xp = npv;                                                                \
    xq = nqv;                                                                \
  }
            ROT_PAIR(t0, b0);
            ROT_PAIR(t1, b1);
            ROT_PAIR(t2, b2);
#undef ROT_PAIR
            float mg = m2 * inv_m;              // |g|
            float c2 = cc_ * cc_, s2 = ss_ * ss_;
            float cs2m = 2.f * cc_ * ss_ * mg;
            float ntn = c2 * nt + s2 * nb + cs2m;
            nb = s2 * nt + c2 * nb - cs2m;
            nt = ntn;
          }
          // ---- movement write (parity ping-pong), flags, spin, read ----
          float2* wb = (rr & 1) ? A : S1;
          float* wn = (rr & 1) ? n0 : n1;
          wb[tdst * AS + sub] = t0;
          wb[tdst * AS + sub + 16] = t1;
          wb[tdst * AS + sub + 32] = t2;
          wb[bdst * AS + sub] = b0;
          wb[bdst * AS + sub + 16] = b1;
          wb[bdst * AS + sub + 32] = b2;
          if (sub == 0) {
            wn[tdst] = nt;
            wn[bdst] = nb;
          }
          asm volatile("" ::: "memory");   // keep col writes before flag write
          if (sub == 0) {
            if (sendR) ((volatile int*)flagR)[wv] = rr;
            if (sendL) ((volatile int*)flagL)[wv] = rr;
          }
          // spin for neighbor flags (wave0: no left dep; wave5: no right dep)
          {
            volatile int* fR = (volatile int*)flagR;
            volatile int* fL = (volatile int*)flagL;
            int guard = 0;
            if (wv > 0) {
              while (fR[wv - 1] < rr && ++guard < (1 << 22)) {}
            }
            guard = 0;
            if (wv < 5) {
              while (fL[wv + 1] < rr && ++guard < (1 << 22)) {}
            }
          }
          __builtin_amdgcn_sched_barrier(0);
          asm volatile("" ::: "memory");   // no read hoisting above the spin
          t0 = wb[tsrc * AS + sub];
          t1 = wb[tsrc * AS + sub + 16];
          t2 = wb[tsrc * AS + sub + 32];
          b0 = wb[bsrc * AS + sub];
          b1 = wb[bsrc * AS + sub + 16];
          b2 = wb[bsrc * AS + sub + 32];
          nt = wn[tsrc];
          nb = wn[bsrc];
          ++rr;
        }
        // sweep convergence check (global barriers: 2 per 47 rounds)
        unsigned long long bal = __ballot(myActive);
        if ((tid & 63) == 0 && bal != 0ull) sweepFlag = 1;
        __syncthreads();
        int f = sweepFlag;
        __syncthreads();
        if (tid == 0) sweepFlag = 0;
        if (f == 0) break;
      }

      // ---- write final columns to A + exact norms to sig2 ----
      A[tsrc * AS + sub] = t0;
      A[tsrc * AS + sub + 16] = t1;
      A[tsrc * AS + sub + 32] = t2;
      A[bsrc * AS + sub] = b0;
      A[bsrc * AS + sub + 16] = b1;
      A[bsrc * AS + sub + 32] = b2;
      {
        float xt = t0.x * t0.x + t0.y * t0.y + t1.x * t1.x + t1.y * t1.y +
                   t2.x * t2.x + t2.y * t2.y;
        float xb = b0.x * b0.x + b0.y * b0.y + b1.x * b1.x + b1.y * b1.y +
                   b2.x * b2.x + b2.y * b2.y;
        xt = row_reduce16(xt);
        xb = row_reduce16(xb);
        if (sub == 0) {
          sig2[tsrc] = xt;
          sig2[bsrc] = xb;
        }
      }
      __syncthreads();

      // ---- rank columns by sigma^2 (descending, index tie-break) ----
      if (tid < NCOL) {
        float mine = sig2[tid];
        int rk = 0;
        for (int kx = 0; kx < NCOL; ++kx) {
          float o = sig2[kx];
          if (o > mine || (o == mine && kx < tid)) ++rk;
        }
        if (rk < RK) keepSrc[rk] = tid;
      }
      __syncthreads();

      // ---- emit truncated factors ----
      // ci_new[a,s,bn] = A[:,src]/sqrt(sigma)
      for (int o = tid; o < RK * NCOL; o += NTHR) {
        int bn = o / NCOL;
        int row = o % NCOL;  // a*2+s
        int src = keepSrc[bn];
        float sg = sqrtf(sig2[src]);
        float su = rsqrtf(fmaxf(sg, 1e-30f));
        float2 x = A[src * AS + row];
        cores[qg * CORE_ELEMS + row * RK + bn] =
            make_float2(x.x * su, x.y * su);
      }
      // cj_new[bn, col] = sigma^{-3/2} * sum_r conj(A[r,src]) * M0[r,col]
      for (int o = tid; o < RK * NCOL; o += NTHR) {
        int bn = o / NCOL;
        int col = o % NCOL;  // t*24+c
        int src = keepSrc[bn];
        float s2 = fmaxf(sig2[src], 1e-30f);
        float scale = rsqrtf(s2) * rsqrtf(sqrtf(s2));  // sigma^{-3/2}
        float accx = 0.f, accy = 0.f;
        const float2* ac = &A[src * AS];
        const float2* mc = &M0[col * NCOL];
#pragma unroll 8
        for (int rx = 0; rx < NCOL; ++rx) {
          float2 u = ac[rx];
          float2 mm = mc[rx];
          accx += u.x * mm.x + u.y * mm.y;   // conj(u) * m
          accy += u.x * mm.y - u.y * mm.x;
        }
        cores[jg * CORE_ELEMS + bn * (2 * RK) + col] =
            make_float2(accx * scale, accy * scale);
      }
      __syncthreads();
    }
  }
}

// ---------------------------------------------------------------------
// Ring expectation chain
// ---------------------------------------------------------------------
__global__ __launch_bounds__(256) void init_m_kernel(float2* __restrict__ mb) {
  int i = blockIdx.x * 256 + threadIdx.x;
  if (i >= M4) return;
  int r = i % RK;
  int b = (i / RK) % RK;
  int q = (i / (RK * RK)) % RK;
  int p = i / (RK * RK * RK);
  mb[i] = make_float2((p == b && q == r) ? 1.f : 0.f, 0.f);
}

__global__ __launch_bounds__(256) void ring_step_kernel(
    const float2* __restrict__ Min, float2* __restrict__ Mout,
    const float2* __restrict__ cores, int qubit, int zmask) {
  __shared__ float2 Msh[RK * RK];
  __shared__ float2 Ash[CORE_ELEMS];
  __shared__ float2 Tsh[RK * 2 * RK];
  const int pq = blockIdx.x;
  const float zs = ((zmask >> qubit) & 1) ? -1.f : 1.f;
  const float2* minpq = Min + (size_t)pq * (RK * RK);
  for (int o = threadIdx.x; o < RK * RK; o += 256) Msh[o] = minpq[o];
  const float2* Ac = cores + qubit * CORE_ELEMS;
  for (int o = threadIdx.x; o < CORE_ELEMS; o += 256) Ash[o] = Ac[o];
  __syncthreads();
  for (int o = threadIdx.x; o < RK * 2 * RK; o += 256) {
    int r = o / (2 * RK);
    int sc = o % (2 * RK);
    int s = sc / RK, c = sc % RK;
    float sgn = (s == 1) ? zs : 1.f;
    float accx = 0.f, accy = 0.f;
#pragma unroll 8
    for (int b = 0; b < RK; ++b) {
      float2 m = Msh[b * RK + r];
      float2 a = Ash[(b * 2 + s) * RK + c];
      accx += m.x * a.x - m.y * a.y;
      accy += m.x * a.y + m.y * a.x;
    }
    Tsh[o] = make_float2(accx * sgn, accy * sgn);
  }
  __syncthreads();
  float2* moutpq = Mout + (size_t)pq * (RK * RK);
  for (int o = threadIdx.x; o < RK * RK; o += 256) {
    int c = o / RK, d = o % RK;
    float accx = 0.f, accy = 0.f;
    for (int r = 0; r < RK; ++r)
#pragma unroll
      for (int s = 0; s < 2; ++s) {
        float2 t = Tsh[r * (2 * RK) + s * RK + c];
        float2 a = Ash[(r * 2 + s) * RK + d];
        accx += t.x * a.x + t.y * a.y;
        accy += t.y * a.x - t.x * a.y;
      }
    moutpq[o] = make_float2(accx, accy);
  }
}

__global__ __launch_bounds__(256) void trace_kernel(
    const float2* __restrict__ mb, float* __restrict__ dst) {
  __shared__ float sh[4];
  float tr = 0.f;
  for (int o = threadIdx.x; o < RK * RK; o += 256) {
    int p = o / RK, q = o % RK;
    tr += mb[(size_t)o * (RK * RK) + p * RK + q].x;
  }
  for (int d = 1; d < 64; d <<= 1) tr += __shfl_xor(tr, d);
  int wave = threadIdx.x >> 6, lane = threadIdx.x & 63;
  if (lane == 0) sh[wave] = tr;
  __syncthreads();
  if (threadIdx.x == 0) dst[0] = sh[0] + sh[1] + sh[2] + sh[3];
}

__global__ void final_kernel(const float* __restrict__ trs,
                             float* __restrict__ out) {
  if (threadIdx.x == 0)
    out[0] = (0.8f * trs[1] + 0.5f * trs[2]) / trs[0];
}

// ---------------------------------------------------------------------
extern "C" void kernel_launch(void* const* d_in, const int* in_sizes, int n_in,
                              void* d_out, int out_size, void* d_ws,
                              size_t ws_size, hipStream_t stream) {
  const float* params = (const float*)d_in[0];
  float* out = (float*)d_out;
  char* ws = (char*)d_ws;

  const size_t CORES_BYTES = sizeof(h_cores);
  const size_t MB_BYTES = (size_t)M4 * sizeof(float2);
  float2* cores = (float2*)ws;
  float2* B0 = (float2*)(ws + CORES_BYTES);
  float2* B1 = (float2*)(ws + CORES_BYTES + MB_BYTES);
  float2* B2 = (float2*)(ws + CORES_BYTES + 2 * MB_BYTES);
  float* tr_ws = (float*)(ws + CORES_BYTES + 3 * MB_BYTES);

  fill_host_cores();
  hipMemcpyAsync(cores, h_cores, CORES_BYTES, hipMemcpyHostToDevice, stream);

  evolve_kernel<<<1, NTHR, 0, stream>>>(params, cores);

  init_m_kernel<<<(M4 + 255) / 256, 256, 0, stream>>>(B0);
  for (int qb = 4; qb < 20; ++qb) {
    const float2* src = ((qb - 4) & 1) ? B1 : B0;
    float2* dst = ((qb - 4) & 1) ? B0 : B1;
    ring_step_kernel<<<RK * RK, 256, 0, stream>>>(src, dst, cores, qb, 0);
  }
  for (int e = 0; e < 3; ++e) {
    int zm = (e == 0) ? 0 : (e == 1 ? 3 : 8);
    ring_step_kernel<<<RK * RK, 256, 0, stream>>>(B0, B1, cores, 0, zm);
    ring_step_kernel<<<RK * RK, 256, 0, stream>>>(B1, B2, cores, 1, zm);
    ring_step_kernel<<<RK * RK, 256, 0, stream>>>(B2, B1, cores, 2, zm);
    ring_step_kernel<<<RK * RK, 256, 0, stream>>>(B1, B2, cores, 3, zm);
    trace_kernel<<<1, 256, 0, stream>>>(B2, tr_ws + e);
  }
  final_kernel<<<1, 64, 0, stream>>>(tr_ws, out);
}

// Round 8
// 17764.027 us; speedup vs baseline: 1.2519x; 1.2519x over previous
//
#include <hip/hip_runtime.h>
#include <cstdint>
#include <cmath>
#include <cstring>

// =====================================================================
// TensorRingModel: Q=20 qubits, L=4 layers, R=24 bond rank.
//   host:  replicate np.random.default_rng(0) -> initial cores
//   dev :  evolve kernel (single WG, 384 thr; Jacobi on 192 thr =
//          24 teams x 8 lanes, 3 waves): 4x { RY; 20x [merge+CZ ->
//          Brent-Luk register-resident Jacobi (SoA v2f packed math,
//          b128 movement, 8-lane DPP reduce) -> truncate 24 ->
//          sigma^-1.5 * A^H M] }
//   dev :  ring transfer chain + traces -> d_out[0]
// =====================================================================

#define RK 24
#define NQ 20
#define NLAY 4
#define NCOL 48
#define AS 49          // interleaved column stride (float2 units)
#define ASQ 25         // movement column stride (float4 units)
#define NSWEEP 8
#define NTHR 384
#define NACT 192       // Jacobi-active threads: 24 teams x 8 lanes
#define CORE_ELEMS (RK * 2 * RK)      // 1152 complex per core
#define M4 (RK * RK * RK * RK)        // 331776

typedef float v2f __attribute__((ext_vector_type(2)));

// ---------------------------------------------------------------------
// Host-side exact replication of numpy default_rng(0).standard_normal
// ---------------------------------------------------------------------
namespace npyrng {

struct Pcg64 {
  unsigned __int128 state, inc;
  static inline unsigned __int128 mult() {
    return (((unsigned __int128)0x2360ED051FC65DA4ull) << 64) |
           0x4385DF649FCCF645ull;
  }
  inline void step() { state = state * mult() + inc; }
  inline uint64_t next64() {
    step();
    uint64_t hi = (uint64_t)(state >> 64), lo = (uint64_t)state;
    uint64_t v = hi ^ lo;
    unsigned r = (unsigned)(state >> 122);
    return (v >> r) | (v << ((64u - r) & 63u));
  }
  inline double nextDouble() {
    return (double)(next64() >> 11) * (1.0 / 9007199254740992.0);
  }
};

struct ZigTables {
  uint64_t ki[256];
  double wi[256], fi[256];
};

static void build_tables(ZigTables& T) {
  const double NR = 3.6541528853610088;
  const double PI = 3.14159265358979323846;
  double f = std::exp(-0.5 * NR * NR);
  double V = NR * f + std::sqrt(PI / 2.0) * std::erfc(NR / std::sqrt(2.0));
  const double m1 = 4503599627370496.0;  // 2^52
  double q = V / f;
  T.ki[0] = (uint64_t)((NR / q) * m1);
  T.ki[1] = 0;
  T.wi[0] = q / m1;
  T.wi[255] = NR / m1;
  T.fi[0] = 1.0;
  T.fi[255] = f;
  double tn = NR;
  for (int i = 254; i >= 1; --i) {
    double dn = std::sqrt(-2.0 * std::log(V / tn + std::exp(-0.5 * tn * tn)));
    T.ki[i + 1] = (uint64_t)((dn / tn) * m1);
    T.fi[i] = std::exp(-0.5 * dn * dn);
    T.wi[i] = dn / m1;
    tn = dn;
  }
}

static double std_normal(Pcg64& g, const ZigTables& T) {
  const double NR = 3.6541528853610088;
  const double INV_NR = 0.27366123732975828;
  for (;;) {
    uint64_t r = g.next64();
    int idx = (int)(r & 0xff);
    r >>= 8;
    int sign = (int)(r & 1);
    uint64_t rabs = (r >> 1) & 0x000fffffffffffffull;
    double x = (double)rabs * T.wi[idx];
    if (sign) x = -x;
    if (rabs < T.ki[idx]) return x;
    if (idx == 0) {
      for (;;) {
        double xx = -INV_NR * std::log1p(-g.nextDouble());
        double yy = -std::log1p(-g.nextDouble());
        if (yy + yy > xx * xx)
          return ((rabs >> 8) & 1) ? -(NR + xx) : (NR + xx);
      }
    } else {
      if ((T.fi[idx - 1] - T.fi[idx]) * g.nextDouble() + T.fi[idx] <
          std::exp(-0.5 * x * x))
        return x;
    }
  }
}

static void seed_pcg64_numpy0(Pcg64& g) {
  const uint32_t INIT_A = 0x43b0d7e5u, MULT_A = 0x931e8875u;
  const uint32_t INIT_B = 0x8b51f9ddu, MULT_B = 0x58f38dedu;
  const uint32_t MIX_L = 0xca01f9ddu, MIX_R = 0x4973f715u;
  uint32_t pool[4];
  uint32_t hc = INIT_A;
  auto hashf = [&](uint32_t value) -> uint32_t {
    value ^= hc;
    hc *= MULT_A;
    value *= hc;
    value ^= value >> 16;
    return value;
  };
  auto mixf = [&](uint32_t x, uint32_t y) -> uint32_t {
    uint32_t r = x * MIX_L - y * MIX_R;
    r ^= r >> 16;
    return r;
  };
  uint32_t entropy0 = 0u;
  for (int i = 0; i < 4; ++i) pool[i] = hashf(i < 1 ? entropy0 : 0u);
  for (int s = 0; s < 4; ++s)
    for (int d = 0; d < 4; ++d)
      if (s != d) pool[d] = mixf(pool[d], hashf(pool[s]));
  uint32_t w[8];
  uint32_t hb = INIT_B;
  for (int i = 0; i < 8; ++i) {
    uint32_t dv = pool[i & 3];
    dv ^= hb;
    hb *= MULT_B;
    dv *= hb;
    dv ^= dv >> 16;
    w[i] = dv;
  }
  uint64_t v0 = (uint64_t)w[0] | ((uint64_t)w[1] << 32);
  uint64_t v1 = (uint64_t)w[2] | ((uint64_t)w[3] << 32);
  uint64_t v2 = (uint64_t)w[4] | ((uint64_t)w[5] << 32);
  uint64_t v3 = (uint64_t)w[6] | ((uint64_t)w[7] << 32);
  unsigned __int128 initstate = (((unsigned __int128)v0) << 64) | v1;
  unsigned __int128 initseq = (((unsigned __int128)v2) << 64) | v3;
  g.state = 0;
  g.inc = (initseq << 1) | 1;
  g.step();
  g.state += initstate;
  g.step();
}

}  // namespace npyrng

static float h_cores[NQ * CORE_ELEMS * 2];

static void fill_host_cores() {
  npyrng::Pcg64 g;
  npyrng::seed_pcg64_numpy0(g);
  npyrng::ZigTables T;
  npyrng::build_tables(T);
  double re[CORE_ELEMS], im[CORE_ELEMS];
  for (int core = 0; core < NQ; ++core) {
    for (int t = 0; t < CORE_ELEMS; ++t) re[t] = npyrng::std_normal(g, T);
    for (int t = 0; t < CORE_ELEMS; ++t) im[t] = npyrng::std_normal(g, T);
    for (int o = 0; o < CORE_ELEMS; ++o) {
      int a = o / (2 * RK);
      int s = (o / RK) & 1;
      int b = o % RK;
      float baser = (s == 0 && a == b) ? 1.0f : 0.0f;
      float nr = (float)re[o], ni = (float)im[o];
      h_cores[(core * CORE_ELEMS + o) * 2 + 0] = baser + 0.01f * nr;
      h_cores[(core * CORE_ELEMS + o) * 2 + 1] = 0.01f * ni;
    }
  }
}

// ---------------------------------------------------------------------
// 8-lane reduce: quad_perm xor1, xor2, then row_half_mirror (cross-quad
// within the 8-lane half-row). All 8 lanes end with the sum. Pure VALU.
// ---------------------------------------------------------------------
__device__ __forceinline__ float red8(float x) {
  int v;
  v = __builtin_amdgcn_update_dpp(0, __float_as_int(x), 0xB1, 0xf, 0xf, false);
  x += __int_as_float(v);                      // quad_perm [1,0,3,2]  xor1
  v = __builtin_amdgcn_update_dpp(0, __float_as_int(x), 0x4E, 0xf, 0xf, false);
  x += __int_as_float(v);                      // quad_perm [2,3,0,1]  xor2
  v = __builtin_amdgcn_update_dpp(0, __float_as_int(x), 0x141, 0xf, 0xf, false);
  x += __int_as_float(v);                      // row_half_mirror (8-lane)
  return x;
}

// ---------------------------------------------------------------------
// Evolve kernel: 384 threads. Jacobi active on tid<192: 24 teams x 8
// lanes (3 waves). Each lane owns 6 complex rows (6*l8 .. 6*l8+5) of its
// team's two columns, SoA-packed: v2f R-pairs / I-pairs -> v_pk_fma_f32.
// Movement via float4 ping-pong buffers (ds_*_b128), barrier per round.
// Waves 3-5 execute the identical barrier sequence (no work).
// ---------------------------------------------------------------------
__global__ __launch_bounds__(NTHR) void evolve_kernel(
    const float* __restrict__ params, float2* __restrict__ cores) {
  __shared__ float2 A[NCOL * AS];      // interleaved: merge + emit storage
  __shared__ float4 A4[NCOL * ASQ];    // movement buf 0 (SoA float4)
  __shared__ float4 S4[NCOL * ASQ];    // movement buf 1
  __shared__ float2 M0[NCOL * NCOL];   // pristine merge matrix (+staging)
  __shared__ float n0[NCOL], n1[NCOL]; // norm staging (ping-pong)
  __shared__ float sig2[NCOL];
  __shared__ int keepSrc[RK];
  __shared__ float csbuf[NQ * 2];
  __shared__ int sweepFlag;

  const int tid = threadIdx.x;
  const bool act = tid < NACT;
  const int team = tid >> 3;    // 0..23 when act
  const int l8 = tid & 7;       // 0..7

  // circle-method movement slots (column positions 0..47)
  const int tdst = (team == 0) ? 0 : ((team < 23) ? team + 1 : 47);
  const int bdst = (team == 0) ? 1 : (23 + team);
  const int tsrc = team, bsrc = 24 + team;

  if (tid == 0) sweepFlag = 0;
  int rr = 0;  // global round counter (ping-pong parity)

  for (int layer = 0; layer < NLAY; ++layer) {
    // ---- RY on every qubit ----
    if (tid < NQ) {
      float half = 0.5f * params[layer * NQ + tid];
      csbuf[2 * tid] = cosf(half);
      csbuf[2 * tid + 1] = sinf(half);
    }
    __syncthreads();
    for (int o = tid; o < NQ * RK * RK; o += NTHR) {
      int qq = o / (RK * RK);
      int ab = o % (RK * RK);
      int a = ab / RK, b = ab % RK;
      float ch = csbuf[2 * qq], sh = csbuf[2 * qq + 1];
      float2* base = cores + qq * CORE_ELEMS;
      float2 c0 = base[(a * 2 + 0) * RK + b];
      float2 c1 = base[(a * 2 + 1) * RK + b];
      base[(a * 2 + 0) * RK + b] =
          make_float2(ch * c0.x - sh * c1.x, ch * c0.y - sh * c1.y);
      base[(a * 2 + 1) * RK + b] =
          make_float2(sh * c0.x + ch * c1.x, sh * c0.y + ch * c1.y);
    }
    __syncthreads();

    // ---- ring of CZ with truncated SVD ----
    for (int qg = 0; qg < NQ; ++qg) {
      int jg = (qg + 1) % NQ;
      const float2* ci = cores + qg * CORE_ELEMS;
      const float2* cj = cores + jg * CORE_ELEMS;

      // stage ci, cj into M0
      for (int o = tid; o < CORE_ELEMS; o += NTHR) {
        M0[o] = ci[o];
        M0[CORE_ELEMS + o] = cj[o];
      }
      __syncthreads();

      // M[(a*2+s)][(t*24+c)] = phase(s,t) * sum_b ci[a,s,b] cj[b,t,c]
      float2 mv[6];
      {
        int k = 0;
        for (int o = tid; o < NCOL * NCOL; o += NTHR, ++k) {
          int col = o / NCOL, row = o % NCOL;
          int a = row >> 1, s = row & 1;
          int t = col / RK, cc = col % RK;
          float accx = 0.f, accy = 0.f;
          for (int b = 0; b < RK; ++b) {
            float2 x = M0[(a * 2 + s) * RK + b];
            float2 y = M0[CORE_ELEMS + (b * 2 + t) * RK + cc];
            accx += x.x * y.x - x.y * y.y;
            accy += x.x * y.y + x.y * y.x;
          }
          if (s == 1 && t == 1) { accx = -accx; accy = -accy; }
          mv[k] = make_float2(accx, accy);
        }
      }
      __syncthreads();
      {
        int k = 0;
        for (int o = tid; o < NCOL * NCOL; o += NTHR, ++k) {
          int col = o / NCOL, row = o % NCOL;
          A[col * AS + row] = mv[k];
          M0[col * NCOL + row] = mv[k];
        }
      }
      __syncthreads();

      // ---- entry: load 2 columns (6 complex/lane) into SoA registers ----
      v2f tR0 = {0, 0}, tR1 = {0, 0}, tR2 = {0, 0};
      v2f tI0 = {0, 0}, tI1 = {0, 0}, tI2 = {0, 0};
      v2f bR0 = {0, 0}, bR1 = {0, 0}, bR2 = {0, 0};
      v2f bI0 = {0, 0}, bI1 = {0, 0}, bI2 = {0, 0};
      float nt = 0.f, nb = 0.f;
      if (act) {
        const float2* cp = &A[tsrc * AS + 6 * l8];
        float2 u0 = cp[0], u1 = cp[1], u2 = cp[2], u3 = cp[3], u4 = cp[4],
               u5 = cp[5];
        tR0 = (v2f){u0.x, u1.x}; tI0 = (v2f){u0.y, u1.y};
        tR1 = (v2f){u2.x, u3.x}; tI1 = (v2f){u2.y, u3.y};
        tR2 = (v2f){u4.x, u5.x}; tI2 = (v2f){u4.y, u5.y};
        cp = &A[bsrc * AS + 6 * l8];
        u0 = cp[0]; u1 = cp[1]; u2 = cp[2]; u3 = cp[3]; u4 = cp[4]; u5 = cp[5];
        bR0 = (v2f){u0.x, u1.x}; bI0 = (v2f){u0.y, u1.y};
        bR1 = (v2f){u2.x, u3.x}; bI1 = (v2f){u2.y, u3.y};
        bR2 = (v2f){u4.x, u5.x}; bI2 = (v2f){u4.y, u5.y};
        v2f Nt = tR0 * tR0 + tI0 * tI0 + tR1 * tR1 + tI1 * tI1 + tR2 * tR2 +
                 tI2 * tI2;
        v2f Nb = bR0 * bR0 + bI0 * bI0 + bR1 * bR1 + bI1 * bI1 + bR2 * bR2 +
                 bI2 * bI2;
        nt = red8(Nt.x + Nt.y);
        nb = red8(Nb.x + Nb.y);
      }
      __syncthreads();

      // ---- Brent-Luk systolic Jacobi ----
      for (int sw = 0; sw < NSWEEP; ++sw) {
        bool myActive = false;
        for (int r = 0; r < 47; ++r) {
          if (act) {
            // packed complex dot: g = t^H b  (SoA, pure pk_fma)
            v2f Pr = tR0 * bR0 + tI0 * bI0;
            Pr += tR1 * bR1 + tI1 * bI1;
            Pr += tR2 * bR2 + tI2 * bI2;
            v2f Pi = tR0 * bI0 - tI0 * bR0;
            Pi += tR1 * bI1 - tI1 * bR1;
            Pi += tR2 * bI2 - tI2 * bR2;
            float pr = red8(Pr.x + Pr.y);
            float pi = red8(Pi.x + Pi.y);
            float m2 = pr * pr + pi * pi;
            myActive = myActive || (m2 > 1e-5f * nt * nb);
            if (m2 > 1e-30f && m2 > 1e-14f * nt * nb) {
              float inv_m = rsqrtf(m2);          // 1/|g|
              float zr = pr * inv_m, zi = pi * inv_m;
              float tau = (nt - nb) * 0.5f * inv_m;
              float tt = 1.f / (fabsf(tau) + sqrtf(1.f + tau * tau));
              if (tau < 0.f) tt = -tt;
              float cc_ = rsqrtf(1.f + tt * tt);
              float ss_ = tt * cc_;
              v2f zrv = {zr, zr}, ziv = {zi, zi};
              v2f ccv = {cc_, cc_}, ssv = {ss_, ss_};
#define ROTK(TR, TI, BR, BI)                                   \
  {                                                            \
    v2f zqR = zrv * BR + ziv * BI;                             \
    v2f zqI = zrv * BI - ziv * BR;                             \
    v2f zpR = zrv * TR - ziv * TI;                             \
    v2f zpI = zrv * TI + ziv * TR;                             \
    TR = ccv * TR + ssv * zqR;                                 \
    TI = ccv * TI + ssv * zqI;                                 \
    BR = ccv * BR - ssv * zpR;                                 \
    BI = ccv * BI - ssv * zpI;                                 \
  }
              ROTK(tR0, tI0, bR0, bI0);
              ROTK(tR1, tI1, bR1, bI1);
              ROTK(tR2, tI2, bR2, bI2);
#undef ROTK
              float mg = m2 * inv_m;             // |g|
              float c2 = cc_ * cc_, s2 = ss_ * ss_;
              float cs2m = 2.f * cc_ * ss_ * mg;
              float ntn = c2 * nt + s2 * nb + cs2m;
              nb = s2 * nt + c2 * nb - cs2m;
              nt = ntn;
            }
            // movement write (b128 x3 per column, ping-pong parity)
            float4* wb = (rr & 1) ? A4 : S4;
            float* wn = (rr & 1) ? n0 : n1;
            int tb = tdst * ASQ + l8 * 3;
            wb[tb + 0] = make_float4(tR0.x, tR0.y, tI0.x, tI0.y);
            wb[tb + 1] = make_float4(tR1.x, tR1.y, tI1.x, tI1.y);
            wb[tb + 2] = make_float4(tR2.x, tR2.y, tI2.x, tI2.y);
            int bb = bdst * ASQ + l8 * 3;
            wb[bb + 0] = make_float4(bR0.x, bR0.y, bI0.x, bI0.y);
            wb[bb + 1] = make_float4(bR1.x, bR1.y, bI1.x, bI1.y);
            wb[bb + 2] = make_float4(bR2.x, bR2.y, bI2.x, bI2.y);
            if (l8 == 0) {
              wn[tdst] = nt;
              wn[bdst] = nb;
            }
          }
          __syncthreads();
          if (act) {
            const float4* wb = (rr & 1) ? A4 : S4;
            const float* wn = (rr & 1) ? n0 : n1;
            int ts = tsrc * ASQ + l8 * 3;
            float4 q0 = wb[ts + 0], q1 = wb[ts + 1], q2 = wb[ts + 2];
            tR0 = (v2f){q0.x, q0.y}; tI0 = (v2f){q0.z, q0.w};
            tR1 = (v2f){q1.x, q1.y}; tI1 = (v2f){q1.z, q1.w};
            tR2 = (v2f){q2.x, q2.y}; tI2 = (v2f){q2.z, q2.w};
            int bs = bsrc * ASQ + l8 * 3;
            q0 = wb[bs + 0]; q1 = wb[bs + 1]; q2 = wb[bs + 2];
            bR0 = (v2f){q0.x, q0.y}; bI0 = (v2f){q0.z, q0.w};
            bR1 = (v2f){q1.x, q1.y}; bI1 = (v2f){q1.z, q1.w};
            bR2 = (v2f){q2.x, q2.y}; bI2 = (v2f){q2.z, q2.w};
            nt = wn[tsrc];
            nb = wn[bsrc];
          }
          ++rr;
        }
        // sweep convergence check
        unsigned long long bal = __ballot(act && myActive);
        if ((tid & 63) == 0 && bal != 0ull) sweepFlag = 1;
        __syncthreads();
        int f = sweepFlag;
        __syncthreads();
        if (tid == 0) sweepFlag = 0;
        if (f == 0) break;
      }

      // ---- exit: unpack to interleaved A + exact norms ----
      if (act) {
        float2* cp = &A[tsrc * AS + 6 * l8];
        cp[0] = make_float2(tR0.x, tI0.x);
        cp[1] = make_float2(tR0.y, tI0.y);
        cp[2] = make_float2(tR1.x, tI1.x);
        cp[3] = make_float2(tR1.y, tI1.y);
        cp[4] = make_float2(tR2.x, tI2.x);
        cp[5] = make_float2(tR2.y, tI2.y);
        cp = &A[bsrc * AS + 6 * l8];
        cp[0] = make_float2(bR0.x, bI0.x);
        cp[1] = make_float2(bR0.y, bI0.y);
        cp[2] = make_float2(bR1.x, bI1.x);
        cp[3] = make_float2(bR1.y, bI1.y);
        cp[4] = make_float2(bR2.x, bI2.x);
        cp[5] = make_float2(bR2.y, bI2.y);
        v2f Nt = tR0 * tR0 + tI0 * tI0 + tR1 * tR1 + tI1 * tI1 + tR2 * tR2 +
                 tI2 * tI2;
        v2f Nb = bR0 * bR0 + bI0 * bI0 + bR1 * bR1 + bI1 * bI1 + bR2 * bR2 +
                 bI2 * bI2;
        float xt = red8(Nt.x + Nt.y);
        float xb = red8(Nb.x + Nb.y);
        if (l8 == 0) {
          sig2[tsrc] = xt;
          sig2[bsrc] = xb;
        }
      }
      __syncthreads();

      // ---- rank columns by sigma^2 (descending, index tie-break) ----
      if (tid < NCOL) {
        float mine = sig2[tid];
        int rk = 0;
        for (int kx = 0; kx < NCOL; ++kx) {
          float o = sig2[kx];
          if (o > mine || (o == mine && kx < tid)) ++rk;
        }
        if (rk < RK) keepSrc[rk] = tid;
      }
      __syncthreads();

      // ---- emit truncated factors ----
      // ci_new[a,s,bn] = A[:,src]/sqrt(sigma)
      for (int o = tid; o < RK * NCOL; o += NTHR) {
        int bn = o / NCOL;
        int row = o % NCOL;  // a*2+s
        int src = keepSrc[bn];
        float sg = sqrtf(sig2[src]);
        float su = rsqrtf(fmaxf(sg, 1e-30f));
        float2 x = A[src * AS + row];
        cores[qg * CORE_ELEMS + row * RK + bn] =
            make_float2(x.x * su, x.y * su);
      }
      // cj_new[bn, col] = sigma^{-3/2} * sum_r conj(A[r,src]) * M0[r,col]
      for (int o = tid; o < RK * NCOL; o += NTHR) {
        int bn = o / NCOL;
        int col = o % NCOL;  // t*24+c
        int src = keepSrc[bn];
        float s2 = fmaxf(sig2[src], 1e-30f);
        float scale = rsqrtf(s2) * rsqrtf(sqrtf(s2));  // sigma^{-3/2}
        float accx = 0.f, accy = 0.f;
        const float2* ac = &A[src * AS];
        const float2* mc = &M0[col * NCOL];
#pragma unroll 8
        for (int rx = 0; rx < NCOL; ++rx) {
          float2 u = ac[rx];
          float2 mm = mc[rx];
          accx += u.x * mm.x + u.y * mm.y;   // conj(u) * m
          accy += u.x * mm.y - u.y * mm.x;
        }
        cores[jg * CORE_ELEMS + bn * (2 * RK) + col] =
            make_float2(accx * scale, accy * scale);
      }
      __syncthreads();
    }
  }
}

// ---------------------------------------------------------------------
// Ring expectation chain
// ---------------------------------------------------------------------
__global__ __launch_bounds__(256) void init_m_kernel(float2* __restrict__ mb) {
  int i = blockIdx.x * 256 + threadIdx.x;
  if (i >= M4) return;
  int r = i % RK;
  int b = (i / RK) % RK;
  int q = (i / (RK * RK)) % RK;
  int p = i / (RK * RK * RK);
  mb[i] = make_float2((p == b && q == r) ? 1.f : 0.f, 0.f);
}

__global__ __launch_bounds__(256) void ring_step_kernel(
    const float2* __restrict__ Min, float2* __restrict__ Mout,
    const float2* __restrict__ cores, int qubit, int zmask) {
  __shared__ float2 Msh[RK * RK];
  __shared__ float2 Ash[CORE_ELEMS];
  __shared__ float2 Tsh[RK * 2 * RK];
  const int pq = blockIdx.x;
  const float zs = ((zmask >> qubit) & 1) ? -1.f : 1.f;
  const float2* minpq = Min + (size_t)pq * (RK * RK);
  for (int o = threadIdx.x; o < RK * RK; o += 256) Msh[o] = minpq[o];
  const float2* Ac = cores + qubit * CORE_ELEMS;
  for (int o = threadIdx.x; o < CORE_ELEMS; o += 256) Ash[o] = Ac[o];
  __syncthreads();
  for (int o = threadIdx.x; o < RK * 2 * RK; o += 256) {
    int r = o / (2 * RK);
    int sc = o % (2 * RK);
    int s = sc / RK, c = sc % RK;
    float sgn = (s == 1) ? zs : 1.f;
    float accx = 0.f, accy = 0.f;
#pragma unroll 8
    for (int b = 0; b < RK; ++b) {
      float2 m = Msh[b * RK + r];
      float2 a = Ash[(b * 2 + s) * RK + c];
      accx += m.x * a.x - m.y * a.y;
      accy += m.x * a.y + m.y * a.x;
    }
    Tsh[o] = make_float2(accx * sgn, accy * sgn);
  }
  __syncthreads();
  float2* moutpq = Mout + (size_t)pq * (RK * RK);
  for (int o = threadIdx.x; o < RK * RK; o += 256) {
    int c = o / RK, d = o % RK;
    float accx = 0.f, accy = 0.f;
    for (int r = 0; r < RK; ++r)
#pragma unroll
      for (int s = 0; s < 2; ++s) {
        float2 t = Tsh[r * (2 * RK) + s * RK + c];
        float2 a = Ash[(r * 2 + s) * RK + d];
        accx += t.x * a.x + t.y * a.y;
        accy += t.y * a.x - t.x * a.y;
      }
    moutpq[o] = make_float2(accx, accy);
  }
}

__global__ __launch_bounds__(256) void trace_kernel(
    const float2* __restrict__ mb, float* __restrict__ dst) {
  __shared__ float sh[4];
  float tr = 0.f;
  for (int o = threadIdx.x; o < RK * RK; o += 256) {
    int p = o / RK, q = o % RK;
    tr += mb[(size_t)o * (RK * RK) + p * RK + q].x;
  }
  for (int d = 1; d < 64; d <<= 1) tr += __shfl_xor(tr, d);
  int wave = threadIdx.x >> 6, lane = threadIdx.x & 63;
  if (lane == 0) sh[wave] = tr;
  __syncthreads();
  if (threadIdx.x == 0) dst[0] = sh[0] + sh[1] + sh[2] + sh[3];
}

__global__ void final_kernel(const float* __restrict__ trs,
                             float* __restrict__ out) {
  if (threadIdx.x == 0)
    out[0] = (0.8f * trs[1] + 0.5f * trs[2]) / trs[0];
}

// ---------------------------------------------------------------------
extern "C" void kernel_launch(void* const* d_in, const int* in_sizes, int n_in,
                              void* d_out, int out_size, void* d_ws,
                              size_t ws_size, hipStream_t stream) {
  const float* params = (const float*)d_in[0];
  float* out = (float*)d_out;
  char* ws = (char*)d_ws;

  const size_t CORES_BYTES = sizeof(h_cores);
  const size_t MB_BYTES = (size_t)M4 * sizeof(float2);
  float2* cores = (float2*)ws;
  float2* B0 = (float2*)(ws + CORES_BYTES);
  float2* B1 = (float2*)(ws + CORES_BYTES + MB_BYTES);
  float2* B2 = (float2*)(ws + CORES_BYTES + 2 * MB_BYTES);
  float* tr_ws = (float*)(ws + CORES_BYTES + 3 * MB_BYTES);

  fill_host_cores();
  hipMemcpyAsync(cores, h_cores, CORES_BYTES, hipMemcpyHostToDevice, stream);

  evolve_kernel<<<1, NTHR, 0, stream>>>(params, cores);

  init_m_kernel<<<(M4 + 255) / 256, 256, 0, stream>>>(B0);
  for (int qb = 4; qb < 20; ++qb) {
    const float2* src = ((qb - 4) & 1) ? B1 : B0;
    float2* dst = ((qb - 4) & 1) ? B0 : B1;
    ring_step_kernel<<<RK * RK, 256, 0, stream>>>(src, dst, cores, qb, 0);
  }
  for (int e = 0; e < 3; ++e) {
    int zm = (e == 0) ? 0 : (e == 1 ? 3 : 8);
    ring_step_kernel<<<RK * RK, 256, 0, stream>>>(B0, B1, cores, 0, zm);
    ring_step_kernel<<<RK * RK, 256, 0, stream>>>(B1, B2, cores, 1, zm);
    ring_step_kernel<<<RK * RK, 256, 0, stream>>>(B2, B1, cores, 2, zm);
    ring_step_kernel<<<RK * RK, 256, 0, stream>>>(B1, B2, cores, 3, zm);
    trace_kernel<<<1, 256, 0, stream>>>(B2, tr_ws + e);
  }
  final_kernel<<<1, 64, 0, stream>>>(tr_ws, out);
}